// Round 2
// baseline (336.895 us; speedup 1.0000x reference)
//
#include <hip/hip_runtime.h>

// x: [64, 3, 512, 512] f32, shifts: [64, 2] i32
// out[b,c,h,w] = x[b,c,(h - s0) & 511, (w - s1) & 511]
#define BATCH 64
#define CHAN  3
#define HH    512
#define WW    512
#define W4    (WW / 4)          // 128 float4 per row
#define ROWS_PER_BLOCK 8        // 8 divides 512 -> a block never crosses a (b,c) image

// Native clang vector type for __builtin_nontemporal_store (HIP float4 is a
// class type the builtin rejects).
typedef float vfloat4 __attribute__((ext_vector_type(4)));

// No LDS, no __syncthreads (avoids the vmcnt(0) barrier drain).
// W-rotation resolved by loading the two adjacent source quads directly:
// consecutive lanes read consecutive quads, so the second load is an L1 hit
// (same or neighboring cache line). 8 rows/block, 4-deep unroll per thread
// gives 8 independent global loads in flight before first use.
__global__ __launch_bounds__(256) void roll_direct_kernel(
    const float4* __restrict__ x,
    const int*    __restrict__ shifts,
    float4*       __restrict__ out)
{
    const int tid  = threadIdx.x;
    const int w4   = tid & (W4 - 1);     // quad index within row
    const int rr   = tid >> 7;           // 0/1: which row of each unroll pair
    const int row0 = blockIdx.x * ROWS_PER_BLOCK;
    const int bc   = row0 >> 9;          // image index (b*3 + c), uniform per block
    const int h0   = row0 & (HH - 1);    // first row of this block within the image
    const int b    = bc / CHAN;          // batch index, uniform per block

    // Wave-uniform shift parameters -> scalar loads / SALU.
    const int s0 = shifts[2 * b];
    const int s1 = shifts[2 * b + 1];
    const int d  = (-s1) & (WW - 1);     // out[w] = in[(w + d) & 511]
    const int qd = d >> 2;               // whole-quad shift
    const int rd = d & 3;                // intra-quad shift (uniform per block)
    const int qa = (w4 + qd) & (W4 - 1);
    const int qb = (qa + 1) & (W4 - 1);

    const float4* __restrict__ xb = x + (size_t)bc * HH * W4;
    float4* __restrict__ ob = out + (size_t)row0 * W4 + w4;

    float4 A[4], Bq[4];
    #pragma unroll
    for (int i = 0; i < 4; ++i) {
        const int h  = h0 + rr + 2 * i;          // covers rows h0..h0+7 across rr/i
        const int hs = (h - s0) & (HH - 1);      // H-rotation: source row
        const float4* __restrict__ src = xb + (size_t)hs * W4;
        A[i]  = src[qa];
        Bq[i] = src[qb];
    }

    #pragma unroll
    for (int i = 0; i < 4; ++i) {
        const float4 a = A[i];
        const float4 q = Bq[i];
        float4 o;
        if      (rd == 0) o = a;
        else if (rd == 1) o = make_float4(a.y, a.z, a.w, q.x);
        else if (rd == 2) o = make_float4(a.z, a.w, q.x, q.y);
        else              o = make_float4(a.w, q.x, q.y, q.z);
        vfloat4* dst = reinterpret_cast<vfloat4*>(&ob[(size_t)(rr + 2 * i) * W4]);
        __builtin_nontemporal_store(__builtin_bit_cast(vfloat4, o), dst);
    }
}

extern "C" void kernel_launch(void* const* d_in, const int* in_sizes, int n_in,
                              void* d_out, int out_size, void* d_ws, size_t ws_size,
                              hipStream_t stream)
{
    const float4* x      = (const float4*)d_in[0];
    const int*    shifts = (const int*)d_in[1];
    float4*       out    = (float4*)d_out;

    const int rows  = BATCH * CHAN * HH;          // 98304
    const int grid  = rows / ROWS_PER_BLOCK;      // 12288 blocks
    const int block = 256;

    roll_direct_kernel<<<grid, block, 0, stream>>>(x, shifts, out);
}

// Round 3
// 327.640 us; speedup vs baseline: 1.0282x; 1.0282x over previous
//
#include <hip/hip_runtime.h>

// x: [64, 3, 512, 512] f32, shifts: [64, 2] i32
// out[b,c,h,w] = x[b,c,(h - s0) & 511, (w - s1) & 511]
#define BATCH 64
#define CHAN  3
#define HH    512
#define WW    512
#define W4    (WW / 4)           // 128 float4 per row
#define ROWS_PER_BLOCK 8         // 8 divides 512 -> block never crosses a (b,c) image

// Proven LDS structure (best measured: 319 us total) with the barrier drain
// amortized: 8 rows per block, 4 global loads per thread issued back-to-back
// before a SINGLE __syncthreads, then 4 stores. One aligned 16B load + one
// aligned 16B store per quad; W-rotation resolved with two adjacent-quad LDS
// reads + wave-uniform funnel select. Plain stores (NT regressed in R2).
__global__ __launch_bounds__(256) void roll_lds8_kernel(
    const float4* __restrict__ x,
    const int*    __restrict__ shifts,
    float4*       __restrict__ out)
{
    __shared__ float4 lds[ROWS_PER_BLOCK * W4];   // 16 KB

    const int tid  = threadIdx.x;
    const int w4   = tid & (W4 - 1);     // quad index within row
    const int rr   = tid >> 7;           // 0/1: row parity within each unroll pair
    const int row0 = blockIdx.x * ROWS_PER_BLOCK;
    const int bc   = row0 >> 9;          // image index (b*3 + c), uniform per block
    const int h0   = row0 & (HH - 1);    // first row of this block within the image
    const int b    = bc / CHAN;          // batch index, uniform per block

    // Wave-uniform shift parameters -> scalar loads / SALU.
    const int s0 = shifts[2 * b];
    const int s1 = shifts[2 * b + 1];

    const float4* __restrict__ xb = x + (size_t)bc * HH * W4;

    // Stage 8 rotated source rows; 4 independent loads in flight per thread,
    // then ONE barrier for the whole block (drain amortized over 32 KB).
    #pragma unroll
    for (int i = 0; i < 4; ++i) {
        const int h  = h0 + rr + 2 * i;          // rows h0..h0+7 across rr/i
        const int hs = (h - s0) & (HH - 1);      // H-rotation source row
        lds[(rr + 2 * i) * W4 + w4] = xb[(size_t)hs * W4 + w4];
    }
    __syncthreads();

    // W-rotation: out[4*w4+k] = row[(4*w4+k+d) & 511], d = (-s1) mod 512
    const int d  = (-s1) & (WW - 1);
    const int qd = d >> 2;               // whole-quad shift
    const int rd = d & 3;                // intra-quad shift (uniform per block)
    const int qa = (w4 + qd) & (W4 - 1);
    const int qb = (qa + 1) & (W4 - 1);

    float4* __restrict__ ob = out + (size_t)row0 * W4;

    #pragma unroll
    for (int i = 0; i < 4; ++i) {
        const int lr = rr + 2 * i;
        const float4 A = lds[lr * W4 + qa];
        const float4 B = lds[lr * W4 + qb];
        float4 o;
        if      (rd == 0) o = A;
        else if (rd == 1) o = make_float4(A.y, A.z, A.w, B.x);
        else if (rd == 2) o = make_float4(A.z, A.w, B.x, B.y);
        else              o = make_float4(A.w, B.x, B.y, B.z);
        ob[(size_t)lr * W4 + w4] = o;
    }
}

extern "C" void kernel_launch(void* const* d_in, const int* in_sizes, int n_in,
                              void* d_out, int out_size, void* d_ws, size_t ws_size,
                              hipStream_t stream)
{
    const float4* x      = (const float4*)d_in[0];
    const int*    shifts = (const int*)d_in[1];
    float4*       out    = (float4*)d_out;

    const int rows  = BATCH * CHAN * HH;          // 98304
    const int grid  = rows / ROWS_PER_BLOCK;      // 12288 blocks
    const int block = 256;

    roll_lds8_kernel<<<grid, block, 0, stream>>>(x, shifts, out);
}

// Round 5
// 317.578 us; speedup vs baseline: 1.0608x; 1.0317x over previous
//
#include <hip/hip_runtime.h>

// x: [64, 3, 512, 512] f32, shifts: [64, 2] i32
// out[b,c,h,w] = x[b,c,(h - s0) & 511, (w - s1) & 511]
#define BATCH 64
#define CHAN  3
#define HH    512
#define WW    512
#define W4    (WW / 4)   // 128 float4 per row

// 16B vector with only 4B alignment guarantee: lets clang emit a single
// global_load_dwordx4 at a dword-aligned address (gfx950 supports unaligned
// global access; worst case it legalizes to 4 coalesced dword loads).
typedef float f4u __attribute__((ext_vector_type(4), aligned(4)));

// Minimal form: the roll is a copy with a per-row byte offset.
// One (possibly dword-aligned) 16B load + one aligned 16B store per quad.
// No LDS, no barrier, no funnel select. Exactly one lane per row wraps past
// the row end and takes a 4-dword gather; d%4==0 blocks take a fully aligned
// uniform fast path.
__global__ __launch_bounds__(256) void roll_copy_kernel(
    const float* __restrict__ x,
    const int*   __restrict__ shifts,
    float*       __restrict__ out)
{
    const int tid    = threadIdx.x;
    const int w4     = tid & (W4 - 1);      // output quad within row
    const int r      = tid >> 7;            // row within block (0/1)
    const int row_id = blockIdx.x * 2 + r;  // global row: bc*512 + h
    const int bc     = row_id >> 9;         // image index (b*3 + c)
    const int h      = row_id & (HH - 1);
    const int b      = bc / CHAN;

    // Wave-uniform shift parameters.
    const int s0 = shifts[2 * b];
    const int s1 = shifts[2 * b + 1];
    const int hs = (h - s0) & (HH - 1);     // H-rotation: source row
    const int d  = (-s1) & (WW - 1);        // out[w] = in[(w + d) & 511]

    const float* __restrict__ xrow = x   + ((size_t)bc * HH + hs) * WW;
    float*       __restrict__ orow = out + (size_t)row_id * WW;

    const int f = (4 * w4 + d) & (WW - 1);  // first source float of this quad

    float4 o;
    if ((d & 3) == 0) {
        // d multiple of 4: f%4==0 and f<=508 -> aligned float4, no wrap.
        o = *(const float4*)(xrow + f);
    } else if (f <= WW - 4) {
        // dword-aligned 16B load, no wrap.
        f4u v = *(const f4u*)(xrow + f);
        o = make_float4(v.x, v.y, v.z, v.w);
    } else {
        // wrap past row end: one lane per row.
        o.x = xrow[f];
        o.y = xrow[(f + 1) & (WW - 1)];
        o.z = xrow[(f + 2) & (WW - 1)];
        o.w = xrow[(f + 3) & (WW - 1)];
    }

    *(float4*)(orow + 4 * w4) = o;
}

extern "C" void kernel_launch(void* const* d_in, const int* in_sizes, int n_in,
                              void* d_out, int out_size, void* d_ws, size_t ws_size,
                              hipStream_t stream)
{
    const float*  x      = (const float*)d_in[0];
    const int*    shifts = (const int*)d_in[1];
    float*        out    = (float*)d_out;

    const int rows  = BATCH * CHAN * HH;   // 98304
    const int grid  = rows / 2;            // 49152 blocks, 2 rows each
    const int block = 256;

    roll_copy_kernel<<<grid, block, 0, stream>>>(x, shifts, out);
}